// Round 1
// baseline (35.313 us; speedup 1.0000x reference)
//
#include <hip/hip_runtime.h>

// ---------------------------------------------------------------------------
// StructuralConstraints: RNA base-pair mask + stacking-energy update.
// ref: mask[b,i,j] = valid(si,sj) * (|i-j|>=3 & i<len & j<len)
//      updated[b,i,j] = bp[b,i,j] + add[b,i,j] + add[b,j,i]
//      add[b,i,j] = S(i,j) + (i>=1 && j<=L-2 ? S(i-1,j+1) : 0)
//      S(r,c) = region(r,c) ? E[seq[r],seq[c],seq[(r+1)%L],seq[(c-1)%L]] : 0
//      region(r,c) = (c-r>=4) & (r<len-1) & (c<len)
// Memory-bound: 64 MiB read + 128 MiB write per call -> ~30us roofline.
// ---------------------------------------------------------------------------

struct ETab { float v[256]; };

constexpr bool vp(int a, int b) { return (a - b == 1) || (b - a == 1); }

constexpr ETab make_E() {
    ETab t{};
    for (int a = 0; a < 4; ++a)
    for (int b = 0; b < 4; ++b)
    for (int c = 0; c < 4; ++c)
    for (int d = 0; d < 4; ++d) {
        float val = 0.0f;
        if (vp(a, b) && vp(c, d)) {
            val = 0.5f;  // default stacking energy
            // STACK overrides (A=0,U=1,G=2,C=3)
            if      (a==0 && b==1 && c==0 && d==1) val = 0.9f;  // (A,U,A,U)
            else if (a==0 && b==1 && c==2 && d==3) val = 1.1f;  // (A,U,G,C)
            else if (a==0 && b==1 && c==2 && d==1) val = 0.8f;  // (A,U,G,U)
            else if (a==2 && b==3 && c==0 && d==1) val = 1.1f;  // (G,C,A,U)
            else if (a==2 && b==3 && c==2 && d==3) val = 1.3f;  // (G,C,G,C)
            else if (a==2 && b==3 && c==2 && d==1) val = 1.0f;  // (G,C,G,U)
            else if (a==2 && b==1 && c==0 && d==1) val = 0.8f;  // (G,U,A,U)
            else if (a==2 && b==1 && c==2 && d==3) val = 1.0f;  // (G,U,G,C)
            else if (a==2 && b==1 && c==2 && d==1) val = 0.7f;  // (G,U,G,U)
        }
        t.v[((a * 4 + b) * 4 + c) * 4 + d] = val;
    }
    return t;
}

__device__ __constant__ ETab cE = make_E();

// One block per (b, i) row; 256 threads; each thread does 4 consecutive j
// (float4 in / 2x float4 out).
__global__ __launch_bounds__(256) void sc_kernel(
    const float* __restrict__ bp,
    const int*   __restrict__ seq,
    const int*   __restrict__ lens,
    float* __restrict__ mask_out,
    float* __restrict__ upd_out,
    int L)
{
    extern __shared__ char smem_raw[];
    int*   sseq = (int*)smem_raw;                          // L ints
    float* T    = (float*)(smem_raw + (size_t)L * 4);      // 64 floats

    const int i   = blockIdx.x;
    const int b   = blockIdx.y;
    const int tid = threadIdx.x;
    const int len = lens[b];
    const int* srow = seq + (size_t)b * L;

    // wave-uniform row codes (scalar loads)
    const int si   = srow[i];
    const int sim1 = srow[(i == 0)     ? (L - 1) : (i - 1)];
    const int sip1 = srow[(i == L - 1) ? 0       : (i + 1)];

    // stage sequence row into LDS (int4, coalesced)
    for (int k = tid; k < (L >> 2); k += blockDim.x)
        ((int4*)sseq)[k] = ((const int4*)srow)[k];

    // per-row E sub-tables: index [p*4+q], 16 entries each -> 16 banks, no conflicts
    if (tid < 64) {
        const int t = tid >> 4;
        const int e = tid & 15;
        const int p = e >> 2, q = e & 3;
        float v;
        if      (t == 0) v = cE.v[((si   * 4 + p) * 4 + sip1) * 4 + q];  // S(i,j):     p=sj,  q=sjm1
        else if (t == 1) v = cE.v[((sim1 * 4 + p) * 4 + si  ) * 4 + q];  // S(i-1,j+1): p=sjp1,q=sj
        else if (t == 2) v = cE.v[((p * 4 + si) * 4 + q) * 4 + sim1];    // S(j,i):     p=sj,  q=sjp1
        else             v = cE.v[((p * 4 + sip1) * 4 + q) * 4 + si];    // S(j-1,i+1): p=sjm1,q=sj
        T[tid] = v;
    }
    __syncthreads();

    const float* T1 = T;
    const float* T2 = T + 16;
    const float* T3 = T + 32;
    const float* T4 = T + 48;

    const size_t rowoff     = ((size_t)b * L + i) * L;
    const bool   i_lt_len   = i < len;
    const bool   i_lt_lenm1 = i < len - 1;
    const bool   ip1_lt_len = (i + 1) < len;
    const bool   i_ge_1     = i >= 1;

    for (int j0 = tid << 2; j0 < L; j0 += (int)blockDim.x << 2) {
        const int4 s4 = *(const int4*)&sseq[j0];
        const int  sm = sseq[(j0 == 0)      ? (L - 1) : (j0 - 1)];
        const int  sp = sseq[(j0 + 4 == L)  ? 0       : (j0 + 4)];
        const int sj[4]  = { s4.x, s4.y, s4.z, s4.w };
        const int sjm[4] = { sm,   s4.x, s4.y, s4.z };
        const int sjp[4] = { s4.y, s4.z, s4.w, sp   };

        const float4 bp4 = *(const float4*)&bp[rowoff + j0];
        const float bpv[4] = { bp4.x, bp4.y, bp4.z, bp4.w };

        float mv[4], uv[4];
        #pragma unroll
        for (int k = 0; k < 4; ++k) {
            const int j = j0 + k;
            const int d = j - i;
            const bool j_lt_len = j < len;

            const bool pair_ok = ((si - sj[k]) == 1) || ((sj[k] - si) == 1);
            mv[k] = (pair_ok && (d >= 3 || d <= -3) && i_lt_len && j_lt_len) ? 1.0f : 0.0f;

            float s = bpv[k];
            if (d >= 2) {           // forward side: S(i,j) + S(i-1,j+1)
                const float s1 = (d >= 4 && i_lt_lenm1 && j_lt_len)
                                   ? T1[sj[k] * 4 + sjm[k]] : 0.0f;
                const float s2 = (i_ge_1 && i_lt_len && (j + 1) < len)
                                   ? T2[sjp[k] * 4 + sj[k]] : 0.0f;
                s += s1 + s2;
            } else if (d <= -2) {   // transposed side: S(j,i) + S(j-1,i+1)
                const float s3 = (d <= -4 && (j < len - 1) && i_lt_len)
                                   ? T3[sj[k] * 4 + sjp[k]] : 0.0f;
                const float s4v = (j >= 1 && j_lt_len && ip1_lt_len)
                                   ? T4[sjm[k] * 4 + sj[k]] : 0.0f;
                s += s3 + s4v;
            }
            uv[k] = s;
        }

        *(float4*)&mask_out[rowoff + j0] = make_float4(mv[0], mv[1], mv[2], mv[3]);
        *(float4*)&upd_out [rowoff + j0] = make_float4(uv[0], uv[1], uv[2], uv[3]);
    }
}

extern "C" void kernel_launch(void* const* d_in, const int* in_sizes, int n_in,
                              void* d_out, int out_size, void* d_ws, size_t ws_size,
                              hipStream_t stream) {
    const float* bp   = (const float*)d_in[0];
    const int*   seq  = (const int*)d_in[1];
    const int*   lens = (const int*)d_in[2];

    const int B = in_sizes[2];
    const int L = in_sizes[1] / B;

    float* mask_out = (float*)d_out;
    float* upd_out  = (float*)d_out + (size_t)B * L * L;

    dim3 grid(L, B);
    const size_t shmem = (size_t)L * sizeof(int) + 64 * sizeof(float);
    sc_kernel<<<grid, 256, shmem, stream>>>(bp, seq, lens, mask_out, upd_out, L);
}